// Round 1
// baseline (401.620 us; speedup 1.0000x reference)
//
#include <hip/hip_runtime.h>
#include <hip/hip_bf16.h>

// Problem constants (from reference setup_inputs):
//   N=8192 nodes, D_IN=512, D_Q=D_K=512, E=262144 edges.
// Key insight: NEG=-1e6 => exp(NEG - m) == 0.0f exactly (fp32 and np),
// so softmax is EXACTLY a sparse softmax over each row's neighbor set.
// Dedup of duplicate edges handled by bitmask adjacency (atomicOr idempotent).

#define N_NODES 8192
#define DIM 512
#define MASK_WORDS 256   // 8192 bits / 32

// ---------------------------------------------------------------------------
// Kernel 1: fused projection GEMM  out = x @ W + b  for W in {Wq, Wk, Wv}
// Classic fp32 LDS-tiled GEMM: BM=64, BN=64, BK=16, 256 thr, 4x4 per thread.
// ---------------------------------------------------------------------------
#define BM 64
#define BN 64
#define BK 16

__global__ __launch_bounds__(256) void proj_gemm(
    const float* __restrict__ x,
    const float* __restrict__ Wq, const float* __restrict__ bq,
    const float* __restrict__ Wk, const float* __restrict__ bk,
    const float* __restrict__ Wv, const float* __restrict__ bv,
    float* __restrict__ q, float* __restrict__ k, float* __restrict__ v)
{
    const int which = blockIdx.z;
    const float* __restrict__ W = (which == 0) ? Wq : (which == 1) ? Wk : Wv;
    const float* __restrict__ b = (which == 0) ? bq : (which == 1) ? bk : bv;
    float* __restrict__ out     = (which == 0) ? q  : (which == 1) ? k  : v;

    const int row0 = blockIdx.y * BM;
    const int col0 = blockIdx.x * BN;
    const int tid = threadIdx.x;
    const int tx = tid & 15;        // 0..15 -> 4 output cols each
    const int ty = tid >> 4;        // 0..15 -> 4 output rows each

    __shared__ float As[BK][BM];    // As[k][m] = x[row0+m][k0+k]
    __shared__ float Bs[BK][BN];    // Bs[k][n] = W[k0+k][col0+n]

    float acc[4][4] = {};

    for (int k0 = 0; k0 < DIM; k0 += BK) {
        // Load A tile: 64x16 = 1024 floats, 4 per thread (float4, same row m)
        {
            int e = tid * 4;
            int m = e >> 4;         // 0..63
            int kk = e & 15;        // 0,4,8,12
            float4 a = *(const float4*)(x + (size_t)(row0 + m) * DIM + k0 + kk);
            As[kk + 0][m] = a.x;
            As[kk + 1][m] = a.y;
            As[kk + 2][m] = a.z;
            As[kk + 3][m] = a.w;
        }
        // Load B tile: 16x64 = 1024 floats, 4 per thread (float4, contiguous n)
        {
            int e = tid * 4;
            int kk = e >> 6;        // 0..15
            int n = e & 63;         // 0..60 step 4
            float4 bb = *(const float4*)(W + (size_t)(k0 + kk) * DIM + col0 + n);
            *(float4*)&Bs[kk][n] = bb;
        }
        __syncthreads();

        #pragma unroll
        for (int kk = 0; kk < BK; ++kk) {
            float a[4], bb[4];
            #pragma unroll
            for (int r = 0; r < 4; ++r) a[r] = As[kk][ty * 4 + r];
            #pragma unroll
            for (int c = 0; c < 4; ++c) bb[c] = Bs[kk][tx * 4 + c];
            #pragma unroll
            for (int r = 0; r < 4; ++r)
                #pragma unroll
                for (int c = 0; c < 4; ++c)
                    acc[r][c] += a[r] * bb[c];
        }
        __syncthreads();
    }

    #pragma unroll
    for (int r = 0; r < 4; ++r) {
        int row = row0 + ty * 4 + r;
        #pragma unroll
        for (int c = 0; c < 4; ++c) {
            int col = col0 + tx * 4 + c;
            out[(size_t)row * DIM + col] = acc[r][c] + b[col];
        }
    }
}

// ---------------------------------------------------------------------------
// Kernel 2: scatter edges into a bitmask adjacency (dedupes duplicates).
// edge_index flat layout: [0..E) = sources, [E..2E) = destinations.
// ---------------------------------------------------------------------------
__global__ void build_mask(const int* __restrict__ ei,
                           unsigned int* __restrict__ mask, int E)
{
    int e = blockIdx.x * blockDim.x + threadIdx.x;
    if (e >= E) return;
    int src = ei[e];
    int dst = ei[E + e];
    atomicOr(&mask[(size_t)src * MASK_WORDS + (dst >> 5)], 1u << (dst & 31));
}

// ---------------------------------------------------------------------------
// Kernel 3: per-row sparse attention. One block (256 thr) per row.
//  - scan bitmask -> neighbor list (LDS, capacity 8192 = worst case, exact)
//  - wave-cooperative dot products q[i] . k[j]
//  - block softmax (2 reductions), then coalesced weighted v accumulation
// ---------------------------------------------------------------------------
__global__ __launch_bounds__(256) void attn_kernel(
    const float* __restrict__ q, const float* __restrict__ k,
    const float* __restrict__ v, const unsigned int* __restrict__ mask,
    float* __restrict__ out)
{
    __shared__ unsigned short nbr[N_NODES];   // 16 KB
    __shared__ float p_lds[N_NODES];          // 32 KB (scores -> weights)
    __shared__ float q_s[DIM];                // 2 KB
    __shared__ float red[8];
    __shared__ int cnt;

    const int row = blockIdx.x;
    const int tid = threadIdx.x;
    const int lane = tid & 63;
    const int wid = tid >> 6;

    if (tid == 0) cnt = 0;
    // load q row (512 floats, 2 per thread)
    ((float2*)q_s)[tid] = *(const float2*)(q + (size_t)row * DIM + tid * 2);
    __syncthreads();

    // scan this row's bitmask: one 32-bit word per thread
    unsigned int mword = mask[(size_t)row * MASK_WORDS + tid];
    while (mword) {
        int bpos = __ffs(mword) - 1;
        mword &= mword - 1;
        int pos = atomicAdd(&cnt, 1);
        nbr[pos] = (unsigned short)(tid * 32 + bpos);
    }
    __syncthreads();
    const int deg = cnt;

    if (deg == 0) {
        // reference: softmax over an all-NEG row -> uniform 1/N weights
        float o0 = 0.f, o1 = 0.f;
        for (int j = 0; j < N_NODES; ++j) {
            const float* vrow = v + (size_t)j * DIM;
            o0 += vrow[tid];
            o1 += vrow[tid + 256];
        }
        out[(size_t)row * DIM + tid]       = o0 * (1.0f / N_NODES);
        out[(size_t)row * DIM + tid + 256] = o1 * (1.0f / N_NODES);
        return;
    }

    // scores: each wave takes neighbors p = wid, wid+4, ...
    const float scale = 0.044194173824159220f;  // 1/sqrt(512)
    for (int p = wid; p < deg; p += 4) {
        int j = nbr[p];
        const float* __restrict__ krow = k + (size_t)j * DIM;
        float s = 0.f;
        #pragma unroll
        for (int t = 0; t < 8; ++t)
            s += q_s[lane + 64 * t] * krow[lane + 64 * t];  // conflict-free LDS, coalesced global
        #pragma unroll
        for (int off = 32; off >= 1; off >>= 1)
            s += __shfl_down(s, off, 64);
        if (lane == 0) p_lds[p] = s * scale;
    }
    __syncthreads();

    // block max
    float m = -3.0e38f;
    for (int p = tid; p < deg; p += 256) m = fmaxf(m, p_lds[p]);
    #pragma unroll
    for (int off = 32; off >= 1; off >>= 1)
        m = fmaxf(m, __shfl_down(m, off, 64));
    if (lane == 0) red[wid] = m;
    __syncthreads();
    m = fmaxf(fmaxf(red[0], red[1]), fmaxf(red[2], red[3]));

    // exp in place + block sum
    float lsum = 0.f;
    for (int p = tid; p < deg; p += 256) {
        float e = expf(p_lds[p] - m);
        p_lds[p] = e;
        lsum += e;
    }
    #pragma unroll
    for (int off = 32; off >= 1; off >>= 1)
        lsum += __shfl_down(lsum, off, 64);
    __syncthreads();                 // everyone done reading red[] (max) & writing p_lds
    if (lane == 0) red[wid] = lsum;
    __syncthreads();
    const float inv_l = 1.0f / (red[0] + red[1] + red[2] + red[3]);

    // weighted accumulation of v rows; thread owns cols tid and tid+256
    float o0 = 0.f, o1 = 0.f;
    for (int p = 0; p < deg; ++p) {
        float w = p_lds[p];          // LDS broadcast
        const float* __restrict__ vrow = v + (size_t)nbr[p] * DIM;
        o0 += w * vrow[tid];         // coalesced across block
        o1 += w * vrow[tid + 256];
    }
    out[(size_t)row * DIM + tid]       = o0 * inv_l;
    out[(size_t)row * DIM + tid + 256] = o1 * inv_l;
}

// ---------------------------------------------------------------------------
extern "C" void kernel_launch(void* const* d_in, const int* in_sizes, int n_in,
                              void* d_out, int out_size, void* d_ws, size_t ws_size,
                              hipStream_t stream)
{
    const float* x  = (const float*)d_in[0];
    const int*   ei = (const int*)d_in[1];      // int32 per harness convention
    const float* Wq = (const float*)d_in[2];
    const float* bq = (const float*)d_in[3];
    const float* Wk = (const float*)d_in[4];
    const float* bk = (const float*)d_in[5];
    const float* Wv = (const float*)d_in[6];
    const float* bv = (const float*)d_in[7];
    float* out = (float*)d_out;

    const int E = in_sizes[1] / 2;

    // workspace layout: q (16MB) | k (16MB) | v (16MB) | mask (8MB) = 56MB
    float* q = (float*)d_ws;
    float* k = q + (size_t)N_NODES * DIM;
    float* v = k + (size_t)N_NODES * DIM;
    unsigned int* mask = (unsigned int*)(v + (size_t)N_NODES * DIM);

    hipMemsetAsync(mask, 0, (size_t)N_NODES * MASK_WORDS * sizeof(unsigned int), stream);

    dim3 gemm_grid(DIM / BN, N_NODES / BM, 3);
    proj_gemm<<<gemm_grid, 256, 0, stream>>>(x, Wq, bq, Wk, bk, Wv, bv, q, k, v);

    build_mask<<<(E + 255) / 256, 256, 0, stream>>>(ei, mask, E);

    attn_kernel<<<N_NODES, 256, 0, stream>>>(q, k, v, mask, out);
}

// Round 2
// 183.670 us; speedup vs baseline: 2.1866x; 2.1866x over previous
//
#include <hip/hip_runtime.h>

// N=8192 nodes, D=512, E=262144. NEG=-1e6 => exp underflows to exactly 0,
// so softmax is EXACTLY sparse over each row's neighbor set (bitmask dedupes
// duplicate edges, matching .at[].set(1.0) idempotence).
//
// Pipeline: convert x,W -> bf16 | MFMA GEMM q,k,v (bf16 out) | bitmask scatter
// | per-row sparse attention (chunked online softmax, exact for any degree).

#define N_NODES 8192
#define DIM 512
#define MASK_WORDS 256   // 8192 bits / 32
#define CAP 2048         // neighbor chunk capacity (64 words * 32 bits)

typedef __attribute__((ext_vector_type(8))) short short8;
typedef __attribute__((ext_vector_type(4))) float f32x4;

__device__ __forceinline__ unsigned short f2bf(float f) {
    unsigned int u = __float_as_uint(f);
    u += 0x7fffu + ((u >> 16) & 1u);          // round-to-nearest-even
    return (unsigned short)(u >> 16);
}
__device__ __forceinline__ float bf_lo(unsigned int w) { return __uint_as_float(w << 16); }
__device__ __forceinline__ float bf_hi(unsigned int w) { return __uint_as_float(w & 0xffff0000u); }

// ---------------------------------------------------------------------------
// x fp32 -> bf16 (element-wise, float4 in / ushort4 out)
// ---------------------------------------------------------------------------
__global__ __launch_bounds__(256) void convert_x(const float* __restrict__ in,
                                                 unsigned short* __restrict__ outp, int n4)
{
    int i = blockIdx.x * 256 + threadIdx.x;
    if (i >= n4) return;
    float4 f = ((const float4*)in)[i];
    ushort4 o;
    o.x = f2bf(f.x); o.y = f2bf(f.y); o.z = f2bf(f.z); o.w = f2bf(f.w);
    ((ushort4*)outp)[i] = o;
}

// ---------------------------------------------------------------------------
// W fp32 [K][N] -> Wt bf16 [N][K] (transposed so GEMM B-tiles are k-contiguous)
// 32x32 LDS tile transpose, 3 matrices via blockIdx.z
// ---------------------------------------------------------------------------
__global__ __launch_bounds__(256) void convert_wT(
    const float* __restrict__ Wq, const float* __restrict__ Wk, const float* __restrict__ Wv,
    unsigned short* __restrict__ Wt)
{
    const int which = blockIdx.z;
    const float* __restrict__ W = (which == 0) ? Wq : (which == 1) ? Wk : Wv;
    unsigned short* __restrict__ outp = Wt + (size_t)which * DIM * DIM;

    __shared__ float t[32][33];
    const int k0 = blockIdx.y * 32, n0 = blockIdx.x * 32;
    const int tx = threadIdx.x & 31, ty = threadIdx.x >> 5;   // ty 0..7
    #pragma unroll
    for (int r = 0; r < 4; ++r)
        t[ty + 8 * r][tx] = W[(size_t)(k0 + ty + 8 * r) * DIM + n0 + tx];
    __syncthreads();
    #pragma unroll
    for (int r = 0; r < 4; ++r)
        outp[(size_t)(n0 + ty + 8 * r) * DIM + k0 + tx] = f2bf(t[tx][ty + 8 * r]);
}

// ---------------------------------------------------------------------------
// bf16 MFMA GEMM: out = x @ W + b, 128x128 tile, BK=32, 4 waves, 4x4 frags/wave
// A: xb [8192][512] bf16 row-major; B: Wt [512][512] bf16 n-major (k-contig)
// ---------------------------------------------------------------------------
__global__ __launch_bounds__(256) void mfma_gemm(
    const unsigned short* __restrict__ xb, const unsigned short* __restrict__ Wt,
    const float* __restrict__ bq, const float* __restrict__ bk, const float* __restrict__ bv,
    unsigned short* __restrict__ q, unsigned short* __restrict__ k, unsigned short* __restrict__ v)
{
    const int which = blockIdx.z;
    const unsigned short* __restrict__ Bm = Wt + (size_t)which * DIM * DIM;
    const float* __restrict__ bias = (which == 0) ? bq : (which == 1) ? bk : bv;
    unsigned short* __restrict__ outp = (which == 0) ? q : (which == 1) ? k : v;

    const int row0 = blockIdx.y * 128;
    const int col0 = blockIdx.x * 128;
    const int tid = threadIdx.x;
    const int lane = tid & 63;
    const int w = tid >> 6;
    const int wm = (w >> 1) * 64;      // wave's 64x64 subtile
    const int wn = (w & 1) * 64;
    const int L = lane & 15;
    const int quad = lane >> 4;

    __shared__ unsigned short As[128 * 32];   // [m][k] 8KB
    __shared__ unsigned short Bs[128 * 32];   // [n][k] 8KB

    f32x4 zero = {0.f, 0.f, 0.f, 0.f};
    f32x4 acc[4][4];
    #pragma unroll
    for (int i = 0; i < 4; ++i)
        #pragma unroll
        for (int j = 0; j < 4; ++j) acc[i][j] = zero;

    for (int k0 = 0; k0 < DIM; k0 += 32) {
        // stage A,B tiles: 512 16B-chunks each, 2 per thread
        #pragma unroll
        for (int c = 0; c < 2; ++c) {
            int ch = tid + c * 256;
            int m = ch >> 2, ko = (ch & 3) << 3;
            *(float4*)&As[m * 32 + ko] =
                *(const float4*)(const void*)(xb + (size_t)(row0 + m) * DIM + k0 + ko);
            *(float4*)&Bs[m * 32 + ko] =
                *(const float4*)(const void*)(Bm + (size_t)(col0 + m) * DIM + k0 + ko);
        }
        __syncthreads();

        short8 a[4], b[4];
        #pragma unroll
        for (int i = 0; i < 4; ++i)
            a[i] = *(const short8*)(const void*)&As[(wm + i * 16 + L) * 32 + quad * 8];
        #pragma unroll
        for (int j = 0; j < 4; ++j)
            b[j] = *(const short8*)(const void*)&Bs[(wn + j * 16 + L) * 32 + quad * 8];

        #pragma unroll
        for (int i = 0; i < 4; ++i)
            #pragma unroll
            for (int j = 0; j < 4; ++j)
                acc[i][j] = __builtin_amdgcn_mfma_f32_16x16x32_bf16(a[i], b[j], acc[i][j], 0, 0, 0);
        __syncthreads();
    }

    // epilogue: C/D layout col = L, row = quad*4 + r
    float biasv[4];
    #pragma unroll
    for (int j = 0; j < 4; ++j) biasv[j] = bias[col0 + wn + j * 16 + L];
    #pragma unroll
    for (int i = 0; i < 4; ++i) {
        int r0 = row0 + wm + i * 16 + quad * 4;
        #pragma unroll
        for (int j = 0; j < 4; ++j) {
            int c = col0 + wn + j * 16 + L;
            #pragma unroll
            for (int r = 0; r < 4; ++r)
                outp[(size_t)(r0 + r) * DIM + c] = f2bf(acc[i][j][r] + biasv[j]);
        }
    }
}

// ---------------------------------------------------------------------------
// edge scatter -> bitmask adjacency (atomicOr dedupes)
// ---------------------------------------------------------------------------
__global__ void build_mask(const int* __restrict__ ei,
                           unsigned int* __restrict__ mask, int E)
{
    int e = blockIdx.x * blockDim.x + threadIdx.x;
    if (e >= E) return;
    int src = ei[e];
    int dst = ei[E + e];
    atomicOr(&mask[(size_t)src * MASK_WORDS + (dst >> 5)], 1u << (dst & 31));
}

// ---------------------------------------------------------------------------
// per-row sparse attention, one 256-thr block per row.
// Chunked online softmax: 1 chunk (all 256 words) when deg<=CAP, else 4 chunks
// of 64 words (<=2048 bits = CAP, exact for any degree).
// ---------------------------------------------------------------------------
__global__ __launch_bounds__(256) void attn_kernel(
    const unsigned short* __restrict__ q, const unsigned short* __restrict__ k,
    const unsigned short* __restrict__ v, const unsigned int* __restrict__ mask,
    float* __restrict__ out)
{
    __shared__ unsigned short nbr[CAP];   // 4KB
    __shared__ float p_lds[CAP];          // 8KB
    __shared__ unsigned short q_s[DIM];   // 1KB
    __shared__ float redm[4], reds[4];
    __shared__ int redi[4];
    __shared__ int cnt;

    const int row = blockIdx.x;
    const int tid = threadIdx.x;
    const int lane = tid & 63;
    const int wid = tid >> 6;

    // q row: 512 bf16 = 256 uints
    ((unsigned int*)q_s)[tid] = ((const unsigned int*)(q + (size_t)row * DIM))[tid];

    // total degree via popcount
    unsigned int mw = mask[(size_t)row * MASK_WORDS + tid];
    int pc = __popc(mw);
    #pragma unroll
    for (int off = 32; off >= 1; off >>= 1) pc += __shfl_down(pc, off, 64);
    if (lane == 0) redi[wid] = pc;
    __syncthreads();
    const int total = redi[0] + redi[1] + redi[2] + redi[3];

    if (total == 0) {
        // all-NEG row -> uniform 1/N weights over all v rows
        float o0 = 0.f, o1 = 0.f;
        for (int j = 0; j < N_NODES; ++j) {
            unsigned int vv = ((const unsigned int*)(v + (size_t)j * DIM))[tid];
            o0 += bf_lo(vv); o1 += bf_hi(vv);
        }
        float2 res; res.x = o0 * (1.0f / N_NODES); res.y = o1 * (1.0f / N_NODES);
        ((float2*)(out + (size_t)row * DIM))[tid] = res;
        return;
    }

    const int nchunks = (total <= CAP) ? 1 : 4;
    const int wpc = (nchunks == 1) ? 256 : 64;   // words per chunk

    float m_run = -3.0e38f, l_run = 0.f;
    float o0 = 0.f, o1 = 0.f;                    // cols 2*tid, 2*tid+1
    const float scale = 0.044194173824159220f;   // 1/sqrt(512)

    for (int c = 0; c < nchunks; ++c) {
        __syncthreads();                          // nbr/p_lds reuse from prev chunk
        if (tid == 0) cnt = 0;
        __syncthreads();
        if (tid < wpc) {
            unsigned int ww = mask[(size_t)row * MASK_WORDS + c * wpc + tid];
            while (ww) {
                int b = __ffs(ww) - 1; ww &= ww - 1;
                int pos = atomicAdd(&cnt, 1);
                nbr[pos] = (unsigned short)((c * wpc + tid) * 32 + b);
            }
        }
        __syncthreads();
        const int cn = cnt;
        if (cn == 0) continue;

        // scores: wave per neighbor
        for (int p = wid; p < cn; p += 4) {
            const unsigned int* __restrict__ krow =
                (const unsigned int*)(k + (size_t)nbr[p] * DIM);
            float s = 0.f;
            #pragma unroll
            for (int t = 0; t < 4; ++t) {
                unsigned int kv = krow[lane + 64 * t];
                unsigned int qv = ((const unsigned int*)q_s)[lane + 64 * t];
                s += bf_lo(qv) * bf_lo(kv) + bf_hi(qv) * bf_hi(kv);
            }
            #pragma unroll
            for (int off = 32; off >= 1; off >>= 1) s += __shfl_down(s, off, 64);
            if (lane == 0) p_lds[p] = s * scale;
        }
        __syncthreads();

        // chunk max
        float mc = -3.0e38f;
        for (int p = tid; p < cn; p += 256) mc = fmaxf(mc, p_lds[p]);
        #pragma unroll
        for (int off = 32; off >= 1; off >>= 1) mc = fmaxf(mc, __shfl_down(mc, off, 64));
        if (lane == 0) redm[wid] = mc;
        __syncthreads();
        mc = fmaxf(fmaxf(redm[0], redm[1]), fmaxf(redm[2], redm[3]));
        const float mnew = fmaxf(m_run, mc);
        const float f = __expf(m_run - mnew);     // 0 on first chunk

        // exp in place + chunk sum
        float ls = 0.f;
        for (int p = tid; p < cn; p += 256) {
            float e = __expf(p_lds[p] - mnew);
            p_lds[p] = e;
            ls += e;
        }
        #pragma unroll
        for (int off = 32; off >= 1; off >>= 1) ls += __shfl_down(ls, off, 64);
        if (lane == 0) reds[wid] = ls;
        __syncthreads();
        l_run = l_run * f + (reds[0] + reds[1] + reds[2] + reds[3]);
        m_run = mnew;
        o0 *= f; o1 *= f;

        // weighted v accumulation (2-unrolled for load ILP)
        int p = 0;
        for (; p + 2 <= cn; p += 2) {
            const unsigned int* v0 = (const unsigned int*)(v + (size_t)nbr[p] * DIM);
            const unsigned int* v1 = (const unsigned int*)(v + (size_t)nbr[p + 1] * DIM);
            float w0 = p_lds[p], w1 = p_lds[p + 1];
            unsigned int a0 = v0[tid], a1 = v1[tid];
            o0 += w0 * bf_lo(a0) + w1 * bf_lo(a1);
            o1 += w0 * bf_hi(a0) + w1 * bf_hi(a1);
        }
        if (p < cn) {
            const unsigned int* v0 = (const unsigned int*)(v + (size_t)nbr[p] * DIM);
            float w0 = p_lds[p];
            unsigned int a0 = v0[tid];
            o0 += w0 * bf_lo(a0);
            o1 += w0 * bf_hi(a0);
        }
    }

    const float inv = 1.0f / l_run;
    float2 res; res.x = o0 * inv; res.y = o1 * inv;
    ((float2*)(out + (size_t)row * DIM))[tid] = res;
}

// ---------------------------------------------------------------------------
extern "C" void kernel_launch(void* const* d_in, const int* in_sizes, int n_in,
                              void* d_out, int out_size, void* d_ws, size_t ws_size,
                              hipStream_t stream)
{
    const float* x  = (const float*)d_in[0];
    const int*   ei = (const int*)d_in[1];
    const float* Wq = (const float*)d_in[2];
    const float* bq = (const float*)d_in[3];
    const float* Wk = (const float*)d_in[4];
    const float* bk = (const float*)d_in[5];
    const float* Wv = (const float*)d_in[6];
    const float* bv = (const float*)d_in[7];
    float* out = (float*)d_out;

    const int E = in_sizes[1] / 2;
    const size_t NM = (size_t)N_NODES * DIM;     // 4,194,304

    // ws layout (bf16 elements): xb | Wt(3) | q | k | v | mask  ~= 41.5 MB
    unsigned short* xb = (unsigned short*)d_ws;
    unsigned short* Wt = xb + NM;
    unsigned short* qb = Wt + (size_t)3 * DIM * DIM;
    unsigned short* kb = qb + NM;
    unsigned short* vb = kb + NM;
    unsigned int* mask = (unsigned int*)(vb + NM);

    hipMemsetAsync(mask, 0, (size_t)N_NODES * MASK_WORDS * sizeof(unsigned int), stream);

    convert_x<<<(int)(NM / 4 / 256), 256, 0, stream>>>(x, xb, (int)(NM / 4));
    convert_wT<<<dim3(16, 16, 3), 256, 0, stream>>>(Wq, Wk, Wv, Wt);
    build_mask<<<(E + 255) / 256, 256, 0, stream>>>(ei, mask, E);

    mfma_gemm<<<dim3(DIM / 128, N_NODES / 128, 3), 256, 0, stream>>>(
        xb, Wt, bq, bk, bv, qb, kb, vb);

    attn_kernel<<<N_NODES, 256, 0, stream>>>(qb, kb, vb, mask, out);
}

// Round 3
// 173.107 us; speedup vs baseline: 2.3201x; 1.0610x over previous
//
#include <hip/hip_runtime.h>

// N=8192 nodes, D=512, E=262144. NEG=-1e6 => exp underflows to exactly 0,
// so softmax is EXACTLY sparse over each row's neighbor set (bitmask dedupes
// duplicate edges, matching .at[].set(1.0) idempotence).
//
// R3: prep fused (convert x, transpose-convert W, edge scatter) |
//     MFMA GEMM with global_load_lds width-16 staging |
//     wave-per-row attention (no block barriers, dwordx4 gathers).

#define N_NODES 8192
#define DIM 512
#define MASK_WORDS 256   // 8192 bits / 32
#define CAPW 512         // neighbor capacity per chunk (per wave)

typedef __attribute__((ext_vector_type(8))) short short8;
typedef __attribute__((ext_vector_type(4))) float f32x4;

__device__ __forceinline__ unsigned short f2bf(float f) {
    unsigned int u = __float_as_uint(f);
    u += 0x7fffu + ((u >> 16) & 1u);          // round-to-nearest-even
    return (unsigned short)(u >> 16);
}
__device__ __forceinline__ float bf_lo(unsigned int w) { return __uint_as_float(w << 16); }
__device__ __forceinline__ float bf_hi(unsigned int w) { return __uint_as_float(w & 0xffff0000u); }

__device__ __forceinline__ float wred_sum(float s) {
    #pragma unroll
    for (int off = 1; off <= 32; off <<= 1) s += __shfl_xor(s, off, 64);
    return s;   // all lanes hold the total
}
__device__ __forceinline__ float wred_max(float s) {
    #pragma unroll
    for (int off = 1; off <= 32; off <<= 1) s = fmaxf(s, __shfl_xor(s, off, 64));
    return s;
}
__device__ __forceinline__ int wred_sumi(int s) {
    #pragma unroll
    for (int off = 1; off <= 32; off <<= 1) s += __shfl_xor(s, off, 64);
    return s;
}
__device__ __forceinline__ float dot8(uint4 a, uint4 b) {
    return bf_lo(a.x) * bf_lo(b.x) + bf_hi(a.x) * bf_hi(b.x)
         + bf_lo(a.y) * bf_lo(b.y) + bf_hi(a.y) * bf_hi(b.y)
         + bf_lo(a.z) * bf_lo(b.z) + bf_hi(a.z) * bf_hi(b.z)
         + bf_lo(a.w) * bf_lo(b.w) + bf_hi(a.w) * bf_hi(b.w);
}

// ---------------------------------------------------------------------------
// prep: [0,4096) convert x -> bf16 | [4096,4864) transpose-convert W -> Wt |
//       [4864,...) scatter edges into bitmask (mask pre-zeroed by memset)
// ---------------------------------------------------------------------------
__global__ __launch_bounds__(256) void prep(
    const float* __restrict__ x, unsigned short* __restrict__ xb,
    const float* __restrict__ Wq, const float* __restrict__ Wk,
    const float* __restrict__ Wv, unsigned short* __restrict__ Wt,
    const int* __restrict__ ei, unsigned int* __restrict__ mask, int E)
{
    __shared__ float sm[32][33];
    const int b = blockIdx.x;
    if (b < 4096) {
        int i = b * 256 + threadIdx.x;          // float4 index, 1M total
        float4 f = ((const float4*)x)[i];
        ushort4 o;
        o.x = f2bf(f.x); o.y = f2bf(f.y); o.z = f2bf(f.z); o.w = f2bf(f.w);
        ((ushort4*)xb)[i] = o;
    } else if (b < 4864) {
        int bb = b - 4096;
        int which = bb >> 8, t = bb & 255;
        const float* __restrict__ W = (which == 0) ? Wq : (which == 1) ? Wk : Wv;
        unsigned short* __restrict__ outp = Wt + (size_t)which * DIM * DIM;
        int n0 = (t & 15) * 32, k0 = (t >> 4) * 32;
        int tx = threadIdx.x & 31, ty = threadIdx.x >> 5;   // ty 0..7
        #pragma unroll
        for (int r = 0; r < 4; ++r)
            sm[ty + 8 * r][tx] = W[(size_t)(k0 + ty + 8 * r) * DIM + n0 + tx];
        __syncthreads();
        #pragma unroll
        for (int r = 0; r < 4; ++r)
            outp[(size_t)(n0 + ty + 8 * r) * DIM + k0 + tx] = f2bf(sm[tx][ty + 8 * r]);
    } else {
        int e = (b - 4864) * 256 + threadIdx.x;
        if (e < E) {
            int src = ei[e];
            int dst = ei[E + e];
            atomicOr(&mask[(size_t)src * MASK_WORDS + (dst >> 5)], 1u << (dst & 31));
        }
    }
}

// ---------------------------------------------------------------------------
// bf16 MFMA GEMM: out = x @ W + b, 128x128 tile, BK=32, 4 waves, 4x4 frags.
// Staging via global_load_lds width=16: LDS chunk ch lands at byte ch*16
// (= wave-uniform base + lane*16, the required pattern).
// ---------------------------------------------------------------------------
__device__ __forceinline__ void load_lds16(const unsigned short* g, unsigned short* l) {
    __builtin_amdgcn_global_load_lds(
        (const __attribute__((address_space(1))) unsigned int*)g,
        (__attribute__((address_space(3))) unsigned int*)l, 16, 0, 0);
}

__global__ __launch_bounds__(256) void mfma_gemm(
    const unsigned short* __restrict__ xb, const unsigned short* __restrict__ Wt,
    const float* __restrict__ bq, const float* __restrict__ bk, const float* __restrict__ bv,
    unsigned short* __restrict__ q, unsigned short* __restrict__ k, unsigned short* __restrict__ v)
{
    const int which = blockIdx.z;
    const unsigned short* __restrict__ Bm = Wt + (size_t)which * DIM * DIM;
    const float* __restrict__ bias = (which == 0) ? bq : (which == 1) ? bk : bv;
    unsigned short* __restrict__ outp = (which == 0) ? q : (which == 1) ? k : v;

    const int row0 = blockIdx.y * 128;
    const int col0 = blockIdx.x * 128;
    const int tid = threadIdx.x;
    const int lane = tid & 63;
    const int w = tid >> 6;
    const int wm = (w >> 1) * 64;
    const int wn = (w & 1) * 64;
    const int L = lane & 15;
    const int quad = lane >> 4;

    __shared__ unsigned short As[128 * 32];   // [m][k] 8KB; chunk ch at byte ch*16
    __shared__ unsigned short Bs[128 * 32];   // [n][k] 8KB

    f32x4 zero = {0.f, 0.f, 0.f, 0.f};
    f32x4 acc[4][4];
    #pragma unroll
    for (int i = 0; i < 4; ++i)
        #pragma unroll
        for (int j = 0; j < 4; ++j) acc[i][j] = zero;

    const int m0 = tid >> 2;             // 0..63
    const int ko = (tid & 3) << 3;       // 0,8,16,24

    for (int k0 = 0; k0 < DIM; k0 += 32) {
        load_lds16(xb + (size_t)(row0 + m0) * DIM + k0 + ko,      As + tid * 8);
        load_lds16(xb + (size_t)(row0 + 64 + m0) * DIM + k0 + ko, As + 2048 + tid * 8);
        load_lds16(Bm + (size_t)(col0 + m0) * DIM + k0 + ko,      Bs + tid * 8);
        load_lds16(Bm + (size_t)(col0 + 64 + m0) * DIM + k0 + ko, Bs + 2048 + tid * 8);
        __syncthreads();

        short8 a[4], bfr[4];
        #pragma unroll
        for (int i = 0; i < 4; ++i)
            a[i] = *(const short8*)(const void*)&As[(wm + i * 16 + L) * 32 + quad * 8];
        #pragma unroll
        for (int j = 0; j < 4; ++j)
            bfr[j] = *(const short8*)(const void*)&Bs[(wn + j * 16 + L) * 32 + quad * 8];

        #pragma unroll
        for (int i = 0; i < 4; ++i)
            #pragma unroll
            for (int j = 0; j < 4; ++j)
                acc[i][j] = __builtin_amdgcn_mfma_f32_16x16x32_bf16(a[i], bfr[j], acc[i][j], 0, 0, 0);
        __syncthreads();
    }

    float biasv[4];
    #pragma unroll
    for (int j = 0; j < 4; ++j) biasv[j] = bias[col0 + wn + j * 16 + L];
    #pragma unroll
    for (int i = 0; i < 4; ++i) {
        int r0 = row0 + wm + i * 16 + quad * 4;
        #pragma unroll
        for (int j = 0; j < 4; ++j) {
            int c = col0 + wn + j * 16 + L;
            #pragma unroll
            for (int r = 0; r < 4; ++r)
                outp[(size_t)(r0 + r) * DIM + c] = f2bf(acc[i][j][r] + biasv[j]);
        }
    }
}

// ---------------------------------------------------------------------------
// attention: wave-per-row (4 rows per 256-thr block), no block barriers.
// q row in registers (uint4/lane), k/v rows as one dwordx4/lane per neighbor.
// Chunked online softmax: 1 chunk of 256 words normally; 16 chunks of 16
// words (<=512 nbrs each) if deg>512 — exact for any degree.
// ---------------------------------------------------------------------------
__global__ __launch_bounds__(256) void attn_kernel(
    const unsigned short* __restrict__ q, const unsigned short* __restrict__ k,
    const unsigned short* __restrict__ v, const unsigned int* __restrict__ mask,
    float* __restrict__ out)
{
    __shared__ unsigned short nbr[4][CAPW];   // 4KB
    __shared__ float pw[4][CAPW];             // 8KB
    __shared__ int cnt[4];

    const int tid = threadIdx.x;
    const int lane = tid & 63;
    const int wid = tid >> 6;
    const int row = blockIdx.x * 4 + wid;

    const uint4 qv = *(const uint4*)(q + (size_t)row * DIM + lane * 8);
    const unsigned int* __restrict__ mrow = mask + (size_t)row * MASK_WORDS;

    // total degree
    int pc = 0;
    #pragma unroll
    for (int t = 0; t < 4; ++t) pc += __popc(mrow[lane + 64 * t]);
    const int total = wred_sumi(pc);

    float o[8];
    #pragma unroll
    for (int i = 0; i < 8; ++i) o[i] = 0.f;

    if (total == 0) {
        // all-NEG row -> uniform 1/N over all v rows (prob ~0, exactness only)
        for (int j = 0; j < N_NODES; ++j) {
            uint4 vv = *(const uint4*)(v + (size_t)j * DIM + lane * 8);
            o[0] += bf_lo(vv.x); o[1] += bf_hi(vv.x);
            o[2] += bf_lo(vv.y); o[3] += bf_hi(vv.y);
            o[4] += bf_lo(vv.z); o[5] += bf_hi(vv.z);
            o[6] += bf_lo(vv.w); o[7] += bf_hi(vv.w);
        }
        float4 r0 = {o[0], o[1], o[2], o[3]};
        float4 r1 = {o[4], o[5], o[6], o[7]};
        const float s = 1.0f / N_NODES;
        r0.x *= s; r0.y *= s; r0.z *= s; r0.w *= s;
        r1.x *= s; r1.y *= s; r1.z *= s; r1.w *= s;
        *(float4*)(out + (size_t)row * DIM + lane * 8) = r0;
        *(float4*)(out + (size_t)row * DIM + lane * 8 + 4) = r1;
        return;
    }

    const int nchunks = (total <= CAPW) ? 1 : 16;
    const int wpc = (nchunks == 1) ? MASK_WORDS : 16;
    const float scale = 0.044194173824159220f;   // 1/sqrt(512)

    float m_run = -3.0e38f, l_run = 0.f;

    for (int c = 0; c < nchunks; ++c) {
        if (lane == 0) cnt[wid] = 0;
        for (int wi = lane; wi < wpc; wi += 64) {
            unsigned int ww = mrow[c * wpc + wi];
            while (ww) {
                int bpos = __ffs(ww) - 1; ww &= ww - 1;
                int pos = atomicAdd(&cnt[wid], 1);
                nbr[wid][pos] = (unsigned short)((c * wpc + wi) * 32 + bpos);
            }
        }
        const int cn = cnt[wid];
        if (cn == 0) continue;

        // scores, 2-unrolled
        for (int p = 0; p < cn; p += 2) {
            int j0 = nbr[wid][p];
            int j1 = nbr[wid][(p + 1 < cn) ? p + 1 : p];
            uint4 k0v = *(const uint4*)(k + (size_t)j0 * DIM + lane * 8);
            uint4 k1v = *(const uint4*)(k + (size_t)j1 * DIM + lane * 8);
            float s0 = wred_sum(dot8(qv, k0v));
            float s1 = wred_sum(dot8(qv, k1v));
            if (lane == 0) {
                pw[wid][p] = s0 * scale;
                if (p + 1 < cn) pw[wid][p + 1] = s1 * scale;
            }
        }

        // chunk softmax (wave-local)
        float mc = -3.0e38f;
        for (int p = lane; p < cn; p += 64) mc = fmaxf(mc, pw[wid][p]);
        mc = wred_max(mc);
        const float mnew = fmaxf(m_run, mc);
        const float f = __expf(m_run - mnew);    // 0 on first chunk
        float ls = 0.f;
        for (int p = lane; p < cn; p += 64) {
            float e = __expf(pw[wid][p] - mnew);
            pw[wid][p] = e;
            ls += e;
        }
        l_run = l_run * f + wred_sum(ls);
        m_run = mnew;
        #pragma unroll
        for (int i = 0; i < 8; ++i) o[i] *= f;

        // weighted v accumulation, 2-unrolled
        int p = 0;
        for (; p + 2 <= cn; p += 2) {
            int j0 = nbr[wid][p], j1 = nbr[wid][p + 1];
            float w0 = pw[wid][p], w1 = pw[wid][p + 1];
            uint4 v0 = *(const uint4*)(v + (size_t)j0 * DIM + lane * 8);
            uint4 v1 = *(const uint4*)(v + (size_t)j1 * DIM + lane * 8);
            o[0] += w0 * bf_lo(v0.x) + w1 * bf_lo(v1.x);
            o[1] += w0 * bf_hi(v0.x) + w1 * bf_hi(v1.x);
            o[2] += w0 * bf_lo(v0.y) + w1 * bf_lo(v1.y);
            o[3] += w0 * bf_hi(v0.y) + w1 * bf_hi(v1.y);
            o[4] += w0 * bf_lo(v0.z) + w1 * bf_lo(v1.z);
            o[5] += w0 * bf_hi(v0.z) + w1 * bf_hi(v1.z);
            o[6] += w0 * bf_lo(v0.w) + w1 * bf_lo(v1.w);
            o[7] += w0 * bf_hi(v0.w) + w1 * bf_hi(v1.w);
        }
        if (p < cn) {
            int j0 = nbr[wid][p];
            float w0 = pw[wid][p];
            uint4 v0 = *(const uint4*)(v + (size_t)j0 * DIM + lane * 8);
            o[0] += w0 * bf_lo(v0.x); o[1] += w0 * bf_hi(v0.x);
            o[2] += w0 * bf_lo(v0.y); o[3] += w0 * bf_hi(v0.y);
            o[4] += w0 * bf_lo(v0.z); o[5] += w0 * bf_hi(v0.z);
            o[6] += w0 * bf_lo(v0.w); o[7] += w0 * bf_hi(v0.w);
        }
    }

    const float inv = 1.0f / l_run;
    float4 r0 = {o[0] * inv, o[1] * inv, o[2] * inv, o[3] * inv};
    float4 r1 = {o[4] * inv, o[5] * inv, o[6] * inv, o[7] * inv};
    *(float4*)(out + (size_t)row * DIM + lane * 8) = r0;
    *(float4*)(out + (size_t)row * DIM + lane * 8 + 4) = r1;
}

// ---------------------------------------------------------------------------
extern "C" void kernel_launch(void* const* d_in, const int* in_sizes, int n_in,
                              void* d_out, int out_size, void* d_ws, size_t ws_size,
                              hipStream_t stream)
{
    const float* x  = (const float*)d_in[0];
    const int*   ei = (const int*)d_in[1];
    const float* Wq = (const float*)d_in[2];
    const float* bq = (const float*)d_in[3];
    const float* Wk = (const float*)d_in[4];
    const float* bk = (const float*)d_in[5];
    const float* Wv = (const float*)d_in[6];
    const float* bv = (const float*)d_in[7];
    float* out = (float*)d_out;

    const int E = in_sizes[1] / 2;
    const size_t NM = (size_t)N_NODES * DIM;     // 4,194,304

    unsigned short* xb = (unsigned short*)d_ws;
    unsigned short* Wt = xb + NM;
    unsigned short* qb = Wt + (size_t)3 * DIM * DIM;
    unsigned short* kb = qb + NM;
    unsigned short* vb = kb + NM;
    unsigned int* mask = (unsigned int*)(vb + NM);

    hipMemsetAsync(mask, 0, (size_t)N_NODES * MASK_WORDS * sizeof(unsigned int), stream);

    prep<<<4864 + (E + 255) / 256, 256, 0, stream>>>(x, xb, Wq, Wk, Wv, Wt, ei, mask, E);

    mfma_gemm<<<dim3(DIM / 128, N_NODES / 128, 3), 256, 0, stream>>>(
        xb, Wt, bq, bk, bv, qb, kb, vb);

    attn_kernel<<<N_NODES / 4, 256, 0, stream>>>(qb, kb, vb, mask, out);
}